// Round 19
// baseline (146.489 us; speedup 1.0000x reference)
//
#include <hip/hip_runtime.h>
#include <hip/hip_cooperative_groups.h>
#include <math.h>

namespace cg = cooperative_groups;

#define BB  4
#define NN  2000
#define TT  24
#define FIN 16
#define HH  128
#define EE  64000
#define CC  6
#define BN  (BB*NN)   // 8000
#define SLOTC 128     // max degree capacity (mean 32, P(>128) ~ 0)

typedef _Float16 f16x8 __attribute__((ext_vector_type(8)));
typedef float f32x4 __attribute__((ext_vector_type(4)));

__device__ __forceinline__ unsigned short f2h(float v) {
    _Float16 h = (_Float16)v;
    return *(unsigned short*)&h;
}

// ---------------- GRU via MFMA + co-launched slot-fill (R17 layout: row-major) -----
// Blocks >= 500: pos = atomicAdd(&cnt[d],1) IS the histogram; slots[d][pos] = s.
// Norm factorizes as dis[d]*sum(dis[s] x[s]). Epilogue premults tw=h@gW1^T and
// tc=h@cW1a^T (weights read row-major). R18 lesson: batch-innermost activation
// layout doubled gru WRITE_SIZE (uncoalesced 2B stores) with zero tail gain.
#define HP2 136
#define GRUB 500

__global__ __launch_bounds__(512) void gru_fill_kernel(
    const float* __restrict__ x,       // [BN][TT][FIN]
    const float* __restrict__ W_hh,    // [384][128]
    const float* __restrict__ W_ih,    // [384][16]
    const float* __restrict__ b_ih, const float* __restrict__ b_hh,
    const float* __restrict__ gW1,     // [128][128] row-major (n,k)
    const float* __restrict__ cW1,     // [128][256] row-major (n,k)
    _Float16* __restrict__ tw16,       // [BN][HH]  h @ gW1^T
    _Float16* __restrict__ tc16,       // [BN][HH]  h @ cW1[:, :128]^T
    const int* __restrict__ src, const int* __restrict__ dst,
    int* __restrict__ cnt, int* __restrict__ slots)
{
    const int tid  = threadIdx.x;

    if (blockIdx.x >= GRUB) {   // slot-fill: 125 blocks x 512 = 64000 edges
        int e = (blockIdx.x - GRUB) * 512 + tid;
        if (e < EE) {
            int d = dst[e], s = src[e];
            int pos = atomicAdd(&cnt[d], 1);
            if (pos < SLOTC) slots[d * SLOTC + pos] = s;
        }
        return;
    }

    const int lane = tid & 63;
    const int w    = tid >> 6;
    const int l15  = lane & 15;
    const int lg   = lane >> 4;
    const int m0   = blockIdx.x * 16;
    const int u    = w * 16 + l15;

    __shared__ __align__(16) unsigned short Hhi[2][16][HP2];   // 8.5 KB
    __shared__ __align__(16) unsigned short Xhi[TT][16][FIN];  // 12 KB

    f16x8 Bh[3][4];
    #pragma unroll
    for (int g = 0; g < 3; ++g) {
        const int col = g * 128 + u;
        #pragma unroll
        for (int kf = 0; kf < 4; ++kf) {
            const float* wp = W_hh + col * 128 + kf * 32 + lg * 8;
            float4 c0 = *(const float4*)wp;
            float4 c1 = *(const float4*)(wp + 4);
            f16x8 b;
            b[0] = (_Float16)c0.x; b[1] = (_Float16)c0.y;
            b[2] = (_Float16)c0.z; b[3] = (_Float16)c0.w;
            b[4] = (_Float16)c1.x; b[5] = (_Float16)c1.y;
            b[6] = (_Float16)c1.z; b[7] = (_Float16)c1.w;
            Bh[g][kf] = b;
        }
    }
    f16x8 Bi[3];
    #pragma unroll
    for (int g = 0; g < 3; ++g) {
        const int col = g * 128 + u;
        f16x8 b;
        #pragma unroll
        for (int i = 0; i < 8; ++i) b[i] = (_Float16)0.0f;
        if (lg < 2) {
            const float* wp = W_ih + col * 16 + lg * 8;
            float4 c0 = *(const float4*)wp;
            float4 c1 = *(const float4*)(wp + 4);
            b[0] = (_Float16)c0.x; b[1] = (_Float16)c0.y;
            b[2] = (_Float16)c0.z; b[3] = (_Float16)c0.w;
            b[4] = (_Float16)c1.x; b[5] = (_Float16)c1.y;
            b[6] = (_Float16)c1.z; b[7] = (_Float16)c1.w;
        } else if (lg == 2) {
            float bias = b_ih[col] + ((g < 2) ? b_hh[col] : 0.0f);
            b[0] = (_Float16)bias;   // k == 16
        }
        Bi[g] = b;
    }

    const float bhn = b_hh[256 + u];
    float hprev[4] = {0.0f, 0.0f, 0.0f, 0.0f};

    for (int i = tid; i < TT * 16 * FIN; i += 512) {
        int t   = i >> 8;
        int rem = i & 255;
        int seq = rem >> 4;
        int f   = rem & 15;
        float v = x[(size_t)(m0 + seq) * (TT * FIN) + t * FIN + f];
        Xhi[t][seq][f] = f2h(v);
    }
    for (int i = tid; i < 16 * HP2; i += 512) (&Hhi[0][0][0])[i] = 0;
    __syncthreads();

    const f32x4 Z4 = (f32x4){0.f, 0.f, 0.f, 0.f};
    f32x4 aR, aZ, aH, aI;

#define IH_SHADOW(tt) do { \
        f16x8 axh; \
        _Float16 zz = (_Float16)0.0f; \
        axh = (f16x8){zz,zz,zz,zz,zz,zz,zz,zz}; \
        if (lg < 2) { \
            axh = *(const f16x8*)&Xhi[tt][l15][lg * 8]; \
        } else if (lg == 2) { \
            axh[0] = (_Float16)1.0f; \
        } \
        aR = __builtin_amdgcn_mfma_f32_16x16x32_f16(axh, Bi[0], Z4, 0, 0, 0); \
        aZ = __builtin_amdgcn_mfma_f32_16x16x32_f16(axh, Bi[1], Z4, 0, 0, 0); \
        aI = __builtin_amdgcn_mfma_f32_16x16x32_f16(axh, Bi[2], Z4, 0, 0, 0); \
        aH = Z4; \
    } while (0)

    IH_SHADOW(0);

    for (int t = 0; t < TT; ++t) {
        const int rb = t & 1, wb = rb ^ 1;

        #pragma unroll
        for (int kf = 0; kf < 4; ++kf) {
            const int ko = kf * 32 + lg * 8;
            f16x8 ahh = *(const f16x8*)&Hhi[rb][l15][ko];
            aR = __builtin_amdgcn_mfma_f32_16x16x32_f16(ahh, Bh[0][kf], aR, 0, 0, 0);
            aZ = __builtin_amdgcn_mfma_f32_16x16x32_f16(ahh, Bh[1][kf], aZ, 0, 0, 0);
            aH = __builtin_amdgcn_mfma_f32_16x16x32_f16(ahh, Bh[2][kf], aH, 0, 0, 0);
        }

        f32x4 aRv = aR, aZv = aZ, aHv = aH, aIv = aI;

        #pragma unroll
        for (int p = 0; p < 4; ++p) {
            float r = __builtin_amdgcn_rcpf(1.0f + __expf(-aRv[p]));
            float z = __builtin_amdgcn_rcpf(1.0f + __expf(-aZv[p]));
            float pre = fmaf(r, aHv[p] + bhn, aIv[p]);
            float e2 = __expf(2.0f * pre);
            float n = fmaf(-2.0f, __builtin_amdgcn_rcpf(e2 + 1.0f), 1.0f);
            float h = fmaf(z, hprev[p] - n, n);
            hprev[p] = h;
            const int seq = lg * 4 + p;
            Hhi[wb][seq][u] = f2h(h);
        }

        if (t + 1 < TT) IH_SHADOW(t + 1);
        __syncthreads();
    }
#undef IH_SHADOW

    // ---- epilogue: final h (fp16) in Hhi[0] (t=23 -> wb=0), barrier passed.
    {
        f32x4 accw = Z4, accc = Z4;
        #pragma unroll
        for (int kf = 0; kf < 4; ++kf) {
            const int ko = kf * 32 + lg * 8;
            f16x8 ah = *(const f16x8*)&Hhi[0][l15][ko];

            const float* wp = gW1 + (size_t)u * 128 + ko;
            float4 c0 = *(const float4*)wp;
            float4 c1 = *(const float4*)(wp + 4);
            f16x8 bw;
            bw[0] = (_Float16)c0.x; bw[1] = (_Float16)c0.y;
            bw[2] = (_Float16)c0.z; bw[3] = (_Float16)c0.w;
            bw[4] = (_Float16)c1.x; bw[5] = (_Float16)c1.y;
            bw[6] = (_Float16)c1.z; bw[7] = (_Float16)c1.w;
            accw = __builtin_amdgcn_mfma_f32_16x16x32_f16(ah, bw, accw, 0, 0, 0);

            const float* cp = cW1 + (size_t)u * 256 + ko;   // cW1a: k < 128
            float4 d0 = *(const float4*)cp;
            float4 d1 = *(const float4*)(cp + 4);
            f16x8 bc;
            bc[0] = (_Float16)d0.x; bc[1] = (_Float16)d0.y;
            bc[2] = (_Float16)d0.z; bc[3] = (_Float16)d0.w;
            bc[4] = (_Float16)d1.x; bc[5] = (_Float16)d1.y;
            bc[6] = (_Float16)d1.z; bc[7] = (_Float16)d1.w;
            accc = __builtin_amdgcn_mfma_f32_16x16x32_f16(ah, bc, accc, 0, 0, 0);
        }
        #pragma unroll
        for (int p = 0; p < 4; ++p) {
            const int row = lg * 4 + p;
            tw16[(size_t)(m0 + row) * HH + u] = (_Float16)accw[p];
            tc16[(size_t)(m0 + row) * HH + u] = (_Float16)accc[p];
        }
    }
}

// ---------------- FUSED GCN: layer1 -> grid.sync -> layer2+classifier --------------
// Cooperative launch: 250 blocks x 1024 thr (<= 256 CUs -> co-residency guaranteed).
// Block owns 8 nodes, processed as two 4-node passes with the proven half-split
// gather (R15/R16 lesson: never lengthen the per-thread edge chain).
__global__ __launch_bounds__(1024) void gcn_fused_kernel(
    const _Float16* __restrict__ tw,   // [BB][NN][HH]
    const int* __restrict__ cnt, const int* __restrict__ slots,
    const float* __restrict__ gb1,
    const float* __restrict__ lg1, const float* __restrict__ lb1,
    const float* __restrict__ gW2,     // [128][128] row-major (n,k)
    _Float16* __restrict__ sw,         // [BB][NN][HH]
    const float* __restrict__ gb2,
    const float* __restrict__ lg2, const float* __restrict__ lb2,
    const float* __restrict__ cW1,     // [128][256] row-major; k in [128,256)
    const _Float16* __restrict__ tc,   // [BN][HH]
    const float* __restrict__ cb1,
    const float* __restrict__ cW2,     // [6][128]
    const float* __restrict__ cb2,
    float* __restrict__ out)           // [BN][CC]
{
    cg::grid_group grid = cg::this_grid();

    const int tid  = threadIdx.x;
    const int nd   = tid >> 8;         // node-within-pass 0..3
    const int t8   = tid & 255;
    const int j    = t8 & 127;
    const int half = t8 >> 7;
    const int n0   = blockIdx.x * 8;

    __shared__ float disL[2048];                         // 8 KB
    __shared__ __align__(16) float pagg[4][BB][HH];      // 8 KB
    __shared__ __align__(16) float agg[4][BB][HH];       // 8 KB
    __shared__ float red[4][2][2][2][2];
    __shared__ __align__(16) unsigned short sL[16][HP2]; // 4.4 KB
    __shared__ __align__(16) float h1L[16][132];         // 8.5 KB

    for (int i = tid; i < 2048; i += 1024)
        disL[i] = rsqrtf(fmaxf((float)cnt[i], 1.0f));
    __syncthreads();

    // =================== LAYER 1: gather(tw) + LN + ReLU + premult(gW2) ============
    #pragma unroll
    for (int g = 0; g < 2; ++g) {
        const int n = n0 + g * 4 + nd;
        const int deg = min(cnt[n], SLOTC);
        const float rd = disL[n];
        const int mid = (deg + 1) >> 1;
        int e        = half ? mid : 0;
        const int e1 = half ? deg : mid;
        const int* sl = slots + (size_t)n * SLOTC;

        float a0 = 0.f, a1 = 0.f, a2 = 0.f, a3 = 0.f;
        for (; e + 1 < e1; e += 2) {
            int   s0 = sl[e],      s1i = sl[e + 1];
            float m0 = disL[s0],   m1  = disL[s1i];
            const _Float16* p0 = tw + (size_t)s0  * HH + j;
            const _Float16* p1 = tw + (size_t)s1i * HH + j;
            a0 = fmaf(m0, (float)p0[0],       a0); a1 = fmaf(m0, (float)p0[NN*HH],   a1);
            a2 = fmaf(m0, (float)p0[2*NN*HH], a2); a3 = fmaf(m0, (float)p0[3*NN*HH], a3);
            a0 = fmaf(m1, (float)p1[0],       a0); a1 = fmaf(m1, (float)p1[NN*HH],   a1);
            a2 = fmaf(m1, (float)p1[2*NN*HH], a2); a3 = fmaf(m1, (float)p1[3*NN*HH], a3);
        }
        if (e < e1) {
            int s0 = sl[e]; float m0 = disL[s0];
            const _Float16* p0 = tw + (size_t)s0 * HH + j;
            a0 = fmaf(m0, (float)p0[0],       a0); a1 = fmaf(m0, (float)p0[NN*HH],   a1);
            a2 = fmaf(m0, (float)p0[2*NN*HH], a2); a3 = fmaf(m0, (float)p0[3*NN*HH], a3);
        }

        if (half) {
            pagg[nd][0][j] = a0; pagg[nd][1][j] = a1;
            pagg[nd][2][j] = a2; pagg[nd][3][j] = a3;
        }
        __syncthreads();
        if (!half) {
            agg[nd][0][j] = a0 + pagg[nd][0][j]; agg[nd][1][j] = a1 + pagg[nd][1][j];
            agg[nd][2][j] = a2 + pagg[nd][2][j]; agg[nd][3][j] = a3 + pagg[nd][3][j];
        }
        __syncthreads();

        const float bj = gb1[j];
        const int b0 = half * 2, b1 = half * 2 + 1;
        float c0 = fmaf(rd, agg[nd][b0][j], bj);
        float c1 = fmaf(rd, agg[nd][b1][j], bj);

        const int lane = t8 & 63, wv = (t8 >> 6) & 1;
        {
            float s1 = c0, s2 = c0 * c0;
            for (int off = 32; off >= 1; off >>= 1) { s1 += __shfl_down(s1, off); s2 += __shfl_down(s2, off); }
            if (lane == 0) { red[nd][half][wv][0][0] = s1; red[nd][half][wv][0][1] = s2; }
            s1 = c1; s2 = c1 * c1;
            for (int off = 32; off >= 1; off >>= 1) { s1 += __shfl_down(s1, off); s2 += __shfl_down(s2, off); }
            if (lane == 0) { red[nd][half][wv][1][0] = s1; red[nd][half][wv][1][1] = s2; }
        }
        __syncthreads();

        const float gj = lg1[j], btj = lb1[j];
        #pragma unroll
        for (int q = 0; q < 2; ++q) {
            float cv = q ? c1 : c0;
            float s1 = red[nd][half][0][q][0] + red[nd][half][1][q][0];
            float s2 = red[nd][half][0][q][1] + red[nd][half][1][q][1];
            float mu = s1 * (1.0f / HH);
            float var = s2 * (1.0f / HH) - mu * mu;
            float y = (cv - mu) * rsqrtf(var + 1e-5f) * gj + btj;
            sL[nd * 4 + (half * 2 + q)][j] = f2h(fmaxf(y, 0.0f));
        }
        __syncthreads();

        if (tid < 512) {    // premult sw[r][u] = sum_k s[r][k] gW2[u][k]
            const int w = tid >> 6, l15 = tid & 15, lg = (tid & 63) >> 4;
            const int u = w * 16 + l15;
            f32x4 acc = (f32x4){0.f, 0.f, 0.f, 0.f};
            #pragma unroll
            for (int kf = 0; kf < 4; ++kf) {
                const int ko = kf * 32 + lg * 8;
                f16x8 a = *(const f16x8*)&sL[l15][ko];
                const float* wp = gW2 + (size_t)u * 128 + ko;
                float4 c0v = *(const float4*)wp;
                float4 c1v = *(const float4*)(wp + 4);
                f16x8 b;
                b[0] = (_Float16)c0v.x; b[1] = (_Float16)c0v.y;
                b[2] = (_Float16)c0v.z; b[3] = (_Float16)c0v.w;
                b[4] = (_Float16)c1v.x; b[5] = (_Float16)c1v.y;
                b[6] = (_Float16)c1v.z; b[7] = (_Float16)c1v.w;
                acc = __builtin_amdgcn_mfma_f32_16x16x32_f16(a, b, acc, 0, 0, 0);
            }
            #pragma unroll
            for (int p = 0; p < 4; ++p) {
                const int r = lg * 4 + p;
                const int nd2 = r >> 2, b2 = r & 3;
                sw[((size_t)b2 * NN + n0 + g * 4 + nd2) * HH + u] = (_Float16)acc[p];
            }
        }
        __syncthreads();
    }

    grid.sync();   // all sw writes visible to all blocks

    // =================== LAYER 2 + classifier ======================================
    #pragma unroll
    for (int g = 0; g < 2; ++g) {
        const int n = n0 + g * 4 + nd;
        const int deg = min(cnt[n], SLOTC);
        const float rd = disL[n];
        const int mid = (deg + 1) >> 1;
        int e        = half ? mid : 0;
        const int e1 = half ? deg : mid;
        const int* sl = slots + (size_t)n * SLOTC;

        float a0 = 0.f, a1 = 0.f, a2 = 0.f, a3 = 0.f;
        for (; e + 1 < e1; e += 2) {
            int   s0 = sl[e],      s1i = sl[e + 1];
            float m0 = disL[s0],   m1  = disL[s1i];
            const _Float16* p0 = sw + (size_t)s0  * HH + j;
            const _Float16* p1 = sw + (size_t)s1i * HH + j;
            a0 = fmaf(m0, (float)p0[0],       a0); a1 = fmaf(m0, (float)p0[NN*HH],   a1);
            a2 = fmaf(m0, (float)p0[2*NN*HH], a2); a3 = fmaf(m0, (float)p0[3*NN*HH], a3);
            a0 = fmaf(m1, (float)p1[0],       a0); a1 = fmaf(m1, (float)p1[NN*HH],   a1);
            a2 = fmaf(m1, (float)p1[2*NN*HH], a2); a3 = fmaf(m1, (float)p1[3*NN*HH], a3);
        }
        if (e < e1) {
            int s0 = sl[e]; float m0 = disL[s0];
            const _Float16* p0 = sw + (size_t)s0 * HH + j;
            a0 = fmaf(m0, (float)p0[0],       a0); a1 = fmaf(m0, (float)p0[NN*HH],   a1);
            a2 = fmaf(m0, (float)p0[2*NN*HH], a2); a3 = fmaf(m0, (float)p0[3*NN*HH], a3);
        }

        if (half) {
            pagg[nd][0][j] = a0; pagg[nd][1][j] = a1;
            pagg[nd][2][j] = a2; pagg[nd][3][j] = a3;
        }
        __syncthreads();
        if (!half) {
            agg[nd][0][j] = a0 + pagg[nd][0][j]; agg[nd][1][j] = a1 + pagg[nd][1][j];
            agg[nd][2][j] = a2 + pagg[nd][2][j]; agg[nd][3][j] = a3 + pagg[nd][3][j];
        }
        __syncthreads();

        const float bj = gb2[j];
        const int b0 = half * 2, b1 = half * 2 + 1;
        float c0 = fmaf(rd, agg[nd][b0][j], bj);
        float c1 = fmaf(rd, agg[nd][b1][j], bj);

        const int lane = t8 & 63, wv = (t8 >> 6) & 1;
        {
            float s1 = c0, s2 = c0 * c0;
            for (int off = 32; off >= 1; off >>= 1) { s1 += __shfl_down(s1, off); s2 += __shfl_down(s2, off); }
            if (lane == 0) { red[nd][half][wv][0][0] = s1; red[nd][half][wv][0][1] = s2; }
            s1 = c1; s2 = c1 * c1;
            for (int off = 32; off >= 1; off >>= 1) { s1 += __shfl_down(s1, off); s2 += __shfl_down(s2, off); }
            if (lane == 0) { red[nd][half][wv][1][0] = s1; red[nd][half][wv][1][1] = s2; }
        }
        __syncthreads();

        const float gj = lg2[j], btj = lb2[j];
        #pragma unroll
        for (int q = 0; q < 2; ++q) {
            float cv = q ? c1 : c0;
            float s1 = red[nd][half][0][q][0] + red[nd][half][1][q][0];
            float s2 = red[nd][half][0][q][1] + red[nd][half][1][q][1];
            float mu = s1 * (1.0f / HH);
            float var = s2 * (1.0f / HH) - mu * mu;
            float y = (cv - mu) * rsqrtf(var + 1e-5f) * gj + btj;
            sL[nd * 4 + (half * 2 + q)][j] = f2h(fmaxf(y, 0.0f));
        }
        __syncthreads();

        if (tid < 512) {    // h1 = ReLU(tc + s2 @ cW1[:,128:]^T + cb1)
            const int w = tid >> 6, l15 = tid & 15, lg = (tid & 63) >> 4;
            const int u = w * 16 + l15;
            f32x4 acc = (f32x4){0.f, 0.f, 0.f, 0.f};
            #pragma unroll
            for (int kf = 0; kf < 4; ++kf) {
                const int ko = kf * 32 + lg * 8;
                f16x8 a = *(const f16x8*)&sL[l15][ko];
                const float* cp = cW1 + (size_t)u * 256 + 128 + ko;
                float4 d0 = *(const float4*)cp;
                float4 d1 = *(const float4*)(cp + 4);
                f16x8 b;
                b[0] = (_Float16)d0.x; b[1] = (_Float16)d0.y;
                b[2] = (_Float16)d0.z; b[3] = (_Float16)d0.w;
                b[4] = (_Float16)d1.x; b[5] = (_Float16)d1.y;
                b[6] = (_Float16)d1.z; b[7] = (_Float16)d1.w;
                acc = __builtin_amdgcn_mfma_f32_16x16x32_f16(a, b, acc, 0, 0, 0);
            }
            const float bu = cb1[u];
            #pragma unroll
            for (int p = 0; p < 4; ++p) {
                const int r = lg * 4 + p;
                const int nd2 = r >> 2, b2 = r & 3;
                const size_t flat = (size_t)b2 * NN + n0 + g * 4 + nd2;
                float tcv = (float)tc[flat * HH + u];
                h1L[r][u] = fmaxf(acc[p] + tcv + bu, 0.0f);
            }
        }
        __syncthreads();

        if (tid < 16 * CC) {
            int r = tid / CC, cc = tid - r * CC;
            const int nd2 = r >> 2, b2 = r & 3;
            const size_t flat = (size_t)b2 * NN + n0 + g * 4 + nd2;
            float a = cb2[cc];
            const float* wp = cW2 + cc * HH;
            #pragma unroll 4
            for (int k = 0; k < HH; ++k) a = fmaf(wp[k], h1L[r][k], a);
            out[flat * CC + cc] = a;
        }
        __syncthreads();
    }
}

// ---------------- launch ----------------
extern "C" void kernel_launch(void* const* d_in, const int* in_sizes, int n_in,
                              void* d_out, int out_size, void* d_ws, size_t ws_size,
                              hipStream_t stream) {
    const float* x    = (const float*)d_in[0];
    const int*   ei   = (const int*)  d_in[1];
    const float* W_ih = (const float*)d_in[2];
    const float* W_hh = (const float*)d_in[3];
    const float* b_ih = (const float*)d_in[4];
    const float* b_hh = (const float*)d_in[5];
    const float* gW1  = (const float*)d_in[6];
    const float* gb1  = (const float*)d_in[7];
    const float* gW2  = (const float*)d_in[8];
    const float* gb2  = (const float*)d_in[9];
    const float* lg1  = (const float*)d_in[10];
    const float* lb1  = (const float*)d_in[11];
    const float* lg2  = (const float*)d_in[12];
    const float* lb2  = (const float*)d_in[13];
    const float* cW1  = (const float*)d_in[14];
    const float* cb1  = (const float*)d_in[15];
    const float* cW2  = (const float*)d_in[16];
    const float* cb2  = (const float*)d_in[17];
    float* out = (float*)d_out;

    float* ws = (float*)d_ws;
    _Float16* tw16 = (_Float16*)ws;  ws += (size_t)BN * HH / 2;
    _Float16* tc16 = (_Float16*)ws;  ws += (size_t)BN * HH / 2;
    _Float16* sw16 = (_Float16*)ws;  ws += (size_t)BN * HH / 2;
    int* ip      = (int*)ws;
    int* cnt     = ip;  ip += 2048;
    int* slots   = ip;  ip += (size_t)NN * SLOTC;

    const int* srcp = ei;
    const int* dstp = ei + EE;

    hipMemsetAsync(cnt, 0, 2048 * sizeof(int), stream);

    gru_fill_kernel<<<GRUB + EE / 512, 512, 0, stream>>>(
        x, W_hh, W_ih, b_ih, b_hh, gW1, cW1, tw16, tc16,
        srcp, dstp, cnt, slots);

    {
        void* args[] = {
            (void*)&tw16, (void*)&cnt, (void*)&slots,
            (void*)&gb1, (void*)&lg1, (void*)&lb1, (void*)&gW2,
            (void*)&sw16,
            (void*)&gb2, (void*)&lg2, (void*)&lb2,
            (void*)&cW1, (void*)&tc16, (void*)&cb1,
            (void*)&cW2, (void*)&cb2, (void*)&out
        };
        hipLaunchCooperativeKernel((const void*)gcn_fused_kernel,
                                   dim3(NN / 8), dim3(1024), args, 0, stream);
    }
}

// Round 20
// 94.059 us; speedup vs baseline: 1.5574x; 1.5574x over previous
//
#include <hip/hip_runtime.h>
#include <math.h>

#define BB  4
#define NN  2000
#define TT  24
#define FIN 16
#define HH  128
#define EE  64000
#define CC  6
#define BN  (BB*NN)   // 8000
#define SLOTC 128     // max degree capacity (mean 32, P(>128) ~ 0)

typedef _Float16 f16x8 __attribute__((ext_vector_type(8)));
typedef float f32x4 __attribute__((ext_vector_type(4)));

__device__ __forceinline__ unsigned short f2h(float v) {
    _Float16 h = (_Float16)v;
    return *(unsigned short*)&h;
}

// ---------------- GRU via MFMA + co-launched slot-fill (R17 proven config) ---------
// Blocks >= 500: pos = atomicAdd(&cnt[d],1) IS the histogram; slots[d][pos] = s.
// GCN norm factorizes as dis[d]*sum(dis[s] x[s]) -> no enorm array.
// Epilogue premults tw=h@gW1^T and tc=h@cW1a^T (weights read row-major).
// R18 lesson: batch-innermost layout doubled WRITE_SIZE for zero tail gain.
// R19 lesson: cooperative grid.sync fusion = 2.5x tail regression (1 block/CU +
// L2 flush). Two small dependent dispatches win.
#define HP2 136
#define GRUB 500

__global__ __launch_bounds__(512) void gru_fill_kernel(
    const float* __restrict__ x,       // [BN][TT][FIN]
    const float* __restrict__ W_hh,    // [384][128]
    const float* __restrict__ W_ih,    // [384][16]
    const float* __restrict__ b_ih, const float* __restrict__ b_hh,
    const float* __restrict__ gW1,     // [128][128] row-major (n,k)
    const float* __restrict__ cW1,     // [128][256] row-major (n,k)
    _Float16* __restrict__ tw16,       // [BN][HH]  h @ gW1^T
    _Float16* __restrict__ tc16,       // [BN][HH]  h @ cW1[:, :128]^T
    const int* __restrict__ src, const int* __restrict__ dst,
    int* __restrict__ cnt, int* __restrict__ slots)
{
    const int tid  = threadIdx.x;

    if (blockIdx.x >= GRUB) {   // slot-fill: 125 blocks x 512 = 64000 edges
        int e = (blockIdx.x - GRUB) * 512 + tid;
        if (e < EE) {
            int d = dst[e], s = src[e];
            int pos = atomicAdd(&cnt[d], 1);
            if (pos < SLOTC) slots[d * SLOTC + pos] = s;
        }
        return;
    }

    const int lane = tid & 63;
    const int w    = tid >> 6;
    const int l15  = lane & 15;
    const int lg   = lane >> 4;
    const int m0   = blockIdx.x * 16;
    const int u    = w * 16 + l15;

    __shared__ __align__(16) unsigned short Hhi[2][16][HP2];   // 8.5 KB
    __shared__ __align__(16) unsigned short Xhi[TT][16][FIN];  // 12 KB

    f16x8 Bh[3][4];
    #pragma unroll
    for (int g = 0; g < 3; ++g) {
        const int col = g * 128 + u;
        #pragma unroll
        for (int kf = 0; kf < 4; ++kf) {
            const float* wp = W_hh + col * 128 + kf * 32 + lg * 8;
            float4 c0 = *(const float4*)wp;
            float4 c1 = *(const float4*)(wp + 4);
            f16x8 b;
            b[0] = (_Float16)c0.x; b[1] = (_Float16)c0.y;
            b[2] = (_Float16)c0.z; b[3] = (_Float16)c0.w;
            b[4] = (_Float16)c1.x; b[5] = (_Float16)c1.y;
            b[6] = (_Float16)c1.z; b[7] = (_Float16)c1.w;
            Bh[g][kf] = b;
        }
    }
    f16x8 Bi[3];
    #pragma unroll
    for (int g = 0; g < 3; ++g) {
        const int col = g * 128 + u;
        f16x8 b;
        #pragma unroll
        for (int i = 0; i < 8; ++i) b[i] = (_Float16)0.0f;
        if (lg < 2) {
            const float* wp = W_ih + col * 16 + lg * 8;
            float4 c0 = *(const float4*)wp;
            float4 c1 = *(const float4*)(wp + 4);
            b[0] = (_Float16)c0.x; b[1] = (_Float16)c0.y;
            b[2] = (_Float16)c0.z; b[3] = (_Float16)c0.w;
            b[4] = (_Float16)c1.x; b[5] = (_Float16)c1.y;
            b[6] = (_Float16)c1.z; b[7] = (_Float16)c1.w;
        } else if (lg == 2) {
            float bias = b_ih[col] + ((g < 2) ? b_hh[col] : 0.0f);
            b[0] = (_Float16)bias;   // k == 16
        }
        Bi[g] = b;
    }

    const float bhn = b_hh[256 + u];
    float hprev[4] = {0.0f, 0.0f, 0.0f, 0.0f};

    for (int i = tid; i < TT * 16 * FIN; i += 512) {
        int t   = i >> 8;
        int rem = i & 255;
        int seq = rem >> 4;
        int f   = rem & 15;
        float v = x[(size_t)(m0 + seq) * (TT * FIN) + t * FIN + f];
        Xhi[t][seq][f] = f2h(v);
    }
    for (int i = tid; i < 16 * HP2; i += 512) (&Hhi[0][0][0])[i] = 0;
    __syncthreads();

    const f32x4 Z4 = (f32x4){0.f, 0.f, 0.f, 0.f};
    f32x4 aR, aZ, aH, aI;

#define IH_SHADOW(tt) do { \
        f16x8 axh; \
        _Float16 zz = (_Float16)0.0f; \
        axh = (f16x8){zz,zz,zz,zz,zz,zz,zz,zz}; \
        if (lg < 2) { \
            axh = *(const f16x8*)&Xhi[tt][l15][lg * 8]; \
        } else if (lg == 2) { \
            axh[0] = (_Float16)1.0f; \
        } \
        aR = __builtin_amdgcn_mfma_f32_16x16x32_f16(axh, Bi[0], Z4, 0, 0, 0); \
        aZ = __builtin_amdgcn_mfma_f32_16x16x32_f16(axh, Bi[1], Z4, 0, 0, 0); \
        aI = __builtin_amdgcn_mfma_f32_16x16x32_f16(axh, Bi[2], Z4, 0, 0, 0); \
        aH = Z4; \
    } while (0)

    IH_SHADOW(0);

    for (int t = 0; t < TT; ++t) {
        const int rb = t & 1, wb = rb ^ 1;

        #pragma unroll
        for (int kf = 0; kf < 4; ++kf) {
            const int ko = kf * 32 + lg * 8;
            f16x8 ahh = *(const f16x8*)&Hhi[rb][l15][ko];
            aR = __builtin_amdgcn_mfma_f32_16x16x32_f16(ahh, Bh[0][kf], aR, 0, 0, 0);
            aZ = __builtin_amdgcn_mfma_f32_16x16x32_f16(ahh, Bh[1][kf], aZ, 0, 0, 0);
            aH = __builtin_amdgcn_mfma_f32_16x16x32_f16(ahh, Bh[2][kf], aH, 0, 0, 0);
        }

        f32x4 aRv = aR, aZv = aZ, aHv = aH, aIv = aI;

        #pragma unroll
        for (int p = 0; p < 4; ++p) {
            float r = __builtin_amdgcn_rcpf(1.0f + __expf(-aRv[p]));
            float z = __builtin_amdgcn_rcpf(1.0f + __expf(-aZv[p]));
            float pre = fmaf(r, aHv[p] + bhn, aIv[p]);
            float e2 = __expf(2.0f * pre);
            float n = fmaf(-2.0f, __builtin_amdgcn_rcpf(e2 + 1.0f), 1.0f);
            float h = fmaf(z, hprev[p] - n, n);
            hprev[p] = h;
            const int seq = lg * 4 + p;
            Hhi[wb][seq][u] = f2h(h);
        }

        if (t + 1 < TT) IH_SHADOW(t + 1);
        __syncthreads();
    }
#undef IH_SHADOW

    // ---- epilogue: final h (fp16) in Hhi[0] (t=23 -> wb=0), barrier passed.
    {
        f32x4 accw = Z4, accc = Z4;
        #pragma unroll
        for (int kf = 0; kf < 4; ++kf) {
            const int ko = kf * 32 + lg * 8;
            f16x8 ah = *(const f16x8*)&Hhi[0][l15][ko];

            const float* wp = gW1 + (size_t)u * 128 + ko;
            float4 c0 = *(const float4*)wp;
            float4 c1 = *(const float4*)(wp + 4);
            f16x8 bw;
            bw[0] = (_Float16)c0.x; bw[1] = (_Float16)c0.y;
            bw[2] = (_Float16)c0.z; bw[3] = (_Float16)c0.w;
            bw[4] = (_Float16)c1.x; bw[5] = (_Float16)c1.y;
            bw[6] = (_Float16)c1.z; bw[7] = (_Float16)c1.w;
            accw = __builtin_amdgcn_mfma_f32_16x16x32_f16(ah, bw, accw, 0, 0, 0);

            const float* cp = cW1 + (size_t)u * 256 + ko;   // cW1a: k < 128
            float4 d0 = *(const float4*)cp;
            float4 d1 = *(const float4*)(cp + 4);
            f16x8 bc;
            bc[0] = (_Float16)d0.x; bc[1] = (_Float16)d0.y;
            bc[2] = (_Float16)d0.z; bc[3] = (_Float16)d0.w;
            bc[4] = (_Float16)d1.x; bc[5] = (_Float16)d1.y;
            bc[6] = (_Float16)d1.z; bc[7] = (_Float16)d1.w;
            accc = __builtin_amdgcn_mfma_f32_16x16x32_f16(ah, bc, accc, 0, 0, 0);
        }
        #pragma unroll
        for (int p = 0; p < 4; ++p) {
            const int row = lg * 4 + p;
            tw16[(size_t)(m0 + row) * HH + u] = (_Float16)accw[p];
            tc16[(size_t)(m0 + row) * HH + u] = (_Float16)accc[p];
        }
    }
}

// ---------------- GCN layer 1: slot gather + LN + ReLU + MFMA premult(gW2) ---------
// 1024 thr = 4 nodes x (128 j x 2 halves). dis table in LDS; norm factorized.
__global__ __launch_bounds__(1024) void gcn1b_kernel(
    const _Float16* __restrict__ tw,
    const int* __restrict__ cnt, const int* __restrict__ slots,
    const float* __restrict__ gb1,
    const float* __restrict__ lg1, const float* __restrict__ lb1,
    const float* __restrict__ gW2,     // [128][128] row-major (n,k)
    _Float16* __restrict__ sw)
{
    const int tid  = threadIdx.x;
    const int nd   = tid >> 8;
    const int t8   = tid & 255;
    const int j    = t8 & 127;
    const int half = t8 >> 7;
    const int n0   = blockIdx.x * 4;
    const int n    = n0 + nd;

    __shared__ float disL[2048];
    for (int i = tid; i < 2048; i += 1024)
        disL[i] = rsqrtf(fmaxf((float)cnt[i], 1.0f));
    __syncthreads();

    const int deg = min(cnt[n], SLOTC);
    const float rd = disL[n];
    const int mid = (deg + 1) >> 1;
    int e        = half ? mid : 0;
    const int e1 = half ? deg : mid;
    const int* sl = slots + (size_t)n * SLOTC;

    float a0 = 0.f, a1 = 0.f, a2 = 0.f, a3 = 0.f;
    for (; e + 1 < e1; e += 2) {
        int   s0 = sl[e],      s1i = sl[e + 1];
        float m0 = disL[s0],   m1  = disL[s1i];
        const _Float16* p0 = tw + (size_t)s0  * HH + j;
        const _Float16* p1 = tw + (size_t)s1i * HH + j;
        a0 = fmaf(m0, (float)p0[0],       a0); a1 = fmaf(m0, (float)p0[NN*HH],   a1);
        a2 = fmaf(m0, (float)p0[2*NN*HH], a2); a3 = fmaf(m0, (float)p0[3*NN*HH], a3);
        a0 = fmaf(m1, (float)p1[0],       a0); a1 = fmaf(m1, (float)p1[NN*HH],   a1);
        a2 = fmaf(m1, (float)p1[2*NN*HH], a2); a3 = fmaf(m1, (float)p1[3*NN*HH], a3);
    }
    if (e < e1) {
        int s0 = sl[e]; float m0 = disL[s0];
        const _Float16* p0 = tw + (size_t)s0 * HH + j;
        a0 = fmaf(m0, (float)p0[0],       a0); a1 = fmaf(m0, (float)p0[NN*HH],   a1);
        a2 = fmaf(m0, (float)p0[2*NN*HH], a2); a3 = fmaf(m0, (float)p0[3*NN*HH], a3);
    }

    __shared__ __align__(16) float pagg[4][BB][HH];   // 8 KB
    __shared__ __align__(16) float agg[4][BB][HH];    // 8 KB
    if (half) {
        pagg[nd][0][j] = a0; pagg[nd][1][j] = a1;
        pagg[nd][2][j] = a2; pagg[nd][3][j] = a3;
    }
    __syncthreads();
    if (!half) {
        agg[nd][0][j] = a0 + pagg[nd][0][j]; agg[nd][1][j] = a1 + pagg[nd][1][j];
        agg[nd][2][j] = a2 + pagg[nd][2][j]; agg[nd][3][j] = a3 + pagg[nd][3][j];
    }
    __syncthreads();

    const float bj = gb1[j];
    const int b0 = half * 2, b1 = half * 2 + 1;
    float c0 = fmaf(rd, agg[nd][b0][j], bj);
    float c1 = fmaf(rd, agg[nd][b1][j], bj);

    const int lane = t8 & 63, wv = (t8 >> 6) & 1;
    __shared__ float red[4][2][2][2][2];   // [nd][half][wv][q][{s1,s2}]
    {
        float s1 = c0, s2 = c0 * c0;
        for (int off = 32; off >= 1; off >>= 1) { s1 += __shfl_down(s1, off); s2 += __shfl_down(s2, off); }
        if (lane == 0) { red[nd][half][wv][0][0] = s1; red[nd][half][wv][0][1] = s2; }
        s1 = c1; s2 = c1 * c1;
        for (int off = 32; off >= 1; off >>= 1) { s1 += __shfl_down(s1, off); s2 += __shfl_down(s2, off); }
        if (lane == 0) { red[nd][half][wv][1][0] = s1; red[nd][half][wv][1][1] = s2; }
    }
    __syncthreads();

    __shared__ __align__(16) unsigned short sL[16][HP2];
    const float gj = lg1[j], btj = lb1[j];
    #pragma unroll
    for (int q = 0; q < 2; ++q) {
        float cv = q ? c1 : c0;
        float s1 = red[nd][half][0][q][0] + red[nd][half][1][q][0];
        float s2 = red[nd][half][0][q][1] + red[nd][half][1][q][1];
        float mu = s1 * (1.0f / HH);
        float var = s2 * (1.0f / HH) - mu * mu;
        float y = (cv - mu) * rsqrtf(var + 1e-5f) * gj + btj;
        sL[nd * 4 + (half * 2 + q)][j] = f2h(fmaxf(y, 0.0f));
    }
    __syncthreads();

    if (tid < 512) {    // waves 0-7: premult sw[r][u] = sum_k s[r][k] gW2[u][k]
        const int w = tid >> 6, l15 = tid & 15, lg = (tid & 63) >> 4;
        const int u = w * 16 + l15;
        f32x4 acc = (f32x4){0.f, 0.f, 0.f, 0.f};
        #pragma unroll
        for (int kf = 0; kf < 4; ++kf) {
            const int ko = kf * 32 + lg * 8;
            f16x8 a = *(const f16x8*)&sL[l15][ko];
            const float* wp = gW2 + (size_t)u * 128 + ko;
            float4 c0v = *(const float4*)wp;
            float4 c1v = *(const float4*)(wp + 4);
            f16x8 b;
            b[0] = (_Float16)c0v.x; b[1] = (_Float16)c0v.y;
            b[2] = (_Float16)c0v.z; b[3] = (_Float16)c0v.w;
            b[4] = (_Float16)c1v.x; b[5] = (_Float16)c1v.y;
            b[6] = (_Float16)c1v.z; b[7] = (_Float16)c1v.w;
            acc = __builtin_amdgcn_mfma_f32_16x16x32_f16(a, b, acc, 0, 0, 0);
        }
        #pragma unroll
        for (int p = 0; p < 4; ++p) {
            const int r = lg * 4 + p;
            const int nd2 = r >> 2, b2 = r & 3;
            sw[((size_t)b2 * NN + n0 + nd2) * HH + u] = (_Float16)acc[p];
        }
    }
}

// ---------------- GCN layer 2 + classifier, fused (slot gather) --------------------
__global__ __launch_bounds__(1024) void gcn2b_cls_kernel(
    const _Float16* __restrict__ sw,
    const int* __restrict__ cnt, const int* __restrict__ slots,
    const float* __restrict__ gb2,
    const float* __restrict__ lg2, const float* __restrict__ lb2,
    const float* __restrict__ cW1,     // [128][256] row-major; k in [128,256)
    const _Float16* __restrict__ tc,
    const float* __restrict__ cb1,
    const float* __restrict__ cW2,     // [6][128]
    const float* __restrict__ cb2,
    float* __restrict__ out)           // [BN][CC]
{
    const int tid  = threadIdx.x;
    const int nd   = tid >> 8;
    const int t8   = tid & 255;
    const int j    = t8 & 127;
    const int half = t8 >> 7;
    const int n0   = blockIdx.x * 4;
    const int n    = n0 + nd;

    __shared__ float disL[2048];
    for (int i = tid; i < 2048; i += 1024)
        disL[i] = rsqrtf(fmaxf((float)cnt[i], 1.0f));
    __syncthreads();

    const int deg = min(cnt[n], SLOTC);
    const float rd = disL[n];
    const int mid = (deg + 1) >> 1;
    int e        = half ? mid : 0;
    const int e1 = half ? deg : mid;
    const int* sl = slots + (size_t)n * SLOTC;

    float a0 = 0.f, a1 = 0.f, a2 = 0.f, a3 = 0.f;
    for (; e + 1 < e1; e += 2) {
        int   s0 = sl[e],      s1i = sl[e + 1];
        float m0 = disL[s0],   m1  = disL[s1i];
        const _Float16* p0 = sw + (size_t)s0  * HH + j;
        const _Float16* p1 = sw + (size_t)s1i * HH + j;
        a0 = fmaf(m0, (float)p0[0],       a0); a1 = fmaf(m0, (float)p0[NN*HH],   a1);
        a2 = fmaf(m0, (float)p0[2*NN*HH], a2); a3 = fmaf(m0, (float)p0[3*NN*HH], a3);
        a0 = fmaf(m1, (float)p1[0],       a0); a1 = fmaf(m1, (float)p1[NN*HH],   a1);
        a2 = fmaf(m1, (float)p1[2*NN*HH], a2); a3 = fmaf(m1, (float)p1[3*NN*HH], a3);
    }
    if (e < e1) {
        int s0 = sl[e]; float m0 = disL[s0];
        const _Float16* p0 = sw + (size_t)s0 * HH + j;
        a0 = fmaf(m0, (float)p0[0],       a0); a1 = fmaf(m0, (float)p0[NN*HH],   a1);
        a2 = fmaf(m0, (float)p0[2*NN*HH], a2); a3 = fmaf(m0, (float)p0[3*NN*HH], a3);
    }

    __shared__ __align__(16) float pagg[4][BB][HH];
    __shared__ __align__(16) float agg[4][BB][HH];
    if (half) {
        pagg[nd][0][j] = a0; pagg[nd][1][j] = a1;
        pagg[nd][2][j] = a2; pagg[nd][3][j] = a3;
    }
    __syncthreads();
    if (!half) {
        agg[nd][0][j] = a0 + pagg[nd][0][j]; agg[nd][1][j] = a1 + pagg[nd][1][j];
        agg[nd][2][j] = a2 + pagg[nd][2][j]; agg[nd][3][j] = a3 + pagg[nd][3][j];
    }
    __syncthreads();

    const float bj = gb2[j];
    const int b0 = half * 2, b1 = half * 2 + 1;
    float c0 = fmaf(rd, agg[nd][b0][j], bj);
    float c1 = fmaf(rd, agg[nd][b1][j], bj);

    const int lane = t8 & 63, wv = (t8 >> 6) & 1;
    __shared__ float red[4][2][2][2][2];
    {
        float s1 = c0, s2 = c0 * c0;
        for (int off = 32; off >= 1; off >>= 1) { s1 += __shfl_down(s1, off); s2 += __shfl_down(s2, off); }
        if (lane == 0) { red[nd][half][wv][0][0] = s1; red[nd][half][wv][0][1] = s2; }
        s1 = c1; s2 = c1 * c1;
        for (int off = 32; off >= 1; off >>= 1) { s1 += __shfl_down(s1, off); s2 += __shfl_down(s2, off); }
        if (lane == 0) { red[nd][half][wv][1][0] = s1; red[nd][half][wv][1][1] = s2; }
    }
    __syncthreads();

    __shared__ __align__(16) unsigned short s2L[16][HP2];
    const float gj = lg2[j], btj = lb2[j];
    #pragma unroll
    for (int q = 0; q < 2; ++q) {
        float cv = q ? c1 : c0;
        float s1 = red[nd][half][0][q][0] + red[nd][half][1][q][0];
        float s2 = red[nd][half][0][q][1] + red[nd][half][1][q][1];
        float mu = s1 * (1.0f / HH);
        float var = s2 * (1.0f / HH) - mu * mu;
        float y = (cv - mu) * rsqrtf(var + 1e-5f) * gj + btj;
        s2L[nd * 4 + (half * 2 + q)][j] = f2h(fmaxf(y, 0.0f));
    }
    __syncthreads();

    __shared__ __align__(16) float h1L[16][132];
    if (tid < 512) {    // h1 = ReLU(tc + s2 @ cW1[:,128:]^T + cb1)
        const int w = tid >> 6, l15 = tid & 15, lg = (tid & 63) >> 4;
        const int u = w * 16 + l15;
        f32x4 acc = (f32x4){0.f, 0.f, 0.f, 0.f};
        #pragma unroll
        for (int kf = 0; kf < 4; ++kf) {
            const int ko = kf * 32 + lg * 8;
            f16x8 a = *(const f16x8*)&s2L[l15][ko];
            const float* cp = cW1 + (size_t)u * 256 + 128 + ko;
            float4 d0 = *(const float4*)cp;
            float4 d1 = *(const float4*)(cp + 4);
            f16x8 b;
            b[0] = (_Float16)d0.x; b[1] = (_Float16)d0.y;
            b[2] = (_Float16)d0.z; b[3] = (_Float16)d0.w;
            b[4] = (_Float16)d1.x; b[5] = (_Float16)d1.y;
            b[6] = (_Float16)d1.z; b[7] = (_Float16)d1.w;
            acc = __builtin_amdgcn_mfma_f32_16x16x32_f16(a, b, acc, 0, 0, 0);
        }
        const float bu = cb1[u];
        #pragma unroll
        for (int p = 0; p < 4; ++p) {
            const int r = lg * 4 + p;
            const int nd2 = r >> 2, b2 = r & 3;
            const size_t flat = (size_t)b2 * NN + n0 + nd2;
            float tcv = (float)tc[flat * HH + u];
            h1L[r][u] = fmaxf(acc[p] + tcv + bu, 0.0f);
        }
    }
    __syncthreads();

    if (tid < 16 * CC) {
        int r = tid / CC, cc = tid - r * CC;
        const int nd2 = r >> 2, b2 = r & 3;
        const size_t flat = (size_t)b2 * NN + n0 + nd2;
        float a = cb2[cc];
        const float* wp = cW2 + cc * HH;
        #pragma unroll 4
        for (int k = 0; k < HH; ++k) a = fmaf(wp[k], h1L[r][k], a);
        out[flat * CC + cc] = a;
    }
}

// ---------------- launch ----------------
extern "C" void kernel_launch(void* const* d_in, const int* in_sizes, int n_in,
                              void* d_out, int out_size, void* d_ws, size_t ws_size,
                              hipStream_t stream) {
    const float* x    = (const float*)d_in[0];
    const int*   ei   = (const int*)  d_in[1];
    const float* W_ih = (const float*)d_in[2];
    const float* W_hh = (const float*)d_in[3];
    const float* b_ih = (const float*)d_in[4];
    const float* b_hh = (const float*)d_in[5];
    const float* gW1  = (const float*)d_in[6];
    const float* gb1  = (const float*)d_in[7];
    const float* gW2  = (const float*)d_in[8];
    const float* gb2  = (const float*)d_in[9];
    const float* lg1  = (const float*)d_in[10];
    const float* lb1  = (const float*)d_in[11];
    const float* lg2  = (const float*)d_in[12];
    const float* lb2  = (const float*)d_in[13];
    const float* cW1  = (const float*)d_in[14];
    const float* cb1  = (const float*)d_in[15];
    const float* cW2  = (const float*)d_in[16];
    const float* cb2  = (const float*)d_in[17];
    float* out = (float*)d_out;

    float* ws = (float*)d_ws;
    _Float16* tw16 = (_Float16*)ws;  ws += (size_t)BN * HH / 2;
    _Float16* tc16 = (_Float16*)ws;  ws += (size_t)BN * HH / 2;
    _Float16* sw16 = (_Float16*)ws;  ws += (size_t)BN * HH / 2;
    int* ip      = (int*)ws;
    int* cnt     = ip;  ip += 2048;
    int* slots   = ip;  ip += (size_t)NN * SLOTC;

    const int* srcp = ei;
    const int* dstp = ei + EE;

    hipMemsetAsync(cnt, 0, 2048 * sizeof(int), stream);

    gru_fill_kernel<<<GRUB + EE / 512, 512, 0, stream>>>(
        x, W_hh, W_ih, b_ih, b_hh, gW1, cW1, tw16, tc16,
        srcp, dstp, cnt, slots);

    gcn1b_kernel<<<NN / 4, 1024, 0, stream>>>(tw16, cnt, slots,
                                              gb1, lg1, lb1, gW2, sw16);

    gcn2b_cls_kernel<<<NN / 4, 1024, 0, stream>>>(sw16, cnt, slots,
                                                  gb2, lg2, lb2, cW1, tc16,
                                                  cb1, cW2, cb2, out);
}